// Round 6
// baseline (300.206 us; speedup 1.0000x reference)
//
#include <hip/hip_runtime.h>

#define C 256
#define N 4096
#define CPG 8
#define GE (CPG * N)
#define JL 2048               // keys per split (split-K = 2)

constexpr float EPS = 1e-5f;
// 32^-0.25 * sqrt(log2(e)) : folded so P = exp2(q'.k') = exp(q.k/sqrt(32))
constexpr float QK_SCALE_E = 0.50500979f;

typedef float f32x4 __attribute__((ext_vector_type(4)));
typedef short s16x8 __attribute__((ext_vector_type(8)));

__device__ __forceinline__ short f2bf(float f) {
    union { float f; unsigned u; } v; v.f = f;
    unsigned r = v.u + 0x7FFFu + ((v.u >> 16) & 1u);  // RNE
    return (short)(r >> 16);
}
__device__ __forceinline__ float bf2f(short s) {
    union { unsigned u; float f; } v; v.u = ((unsigned)(unsigned short)s) << 16;
    return v.f;
}

// ---------------- K1: GroupNorm stats (mean, rstd per (b,g)) ----------------
__global__ __launch_bounds__(1024) void k_stats(const float* __restrict__ x,
                                                float2* __restrict__ stats) {
    int b = blockIdx.x >> 5, g = blockIdx.x & 31;
    size_t base = (size_t)(b * C + g * CPG) * N;
    const float* xp = x + base;
    int tid = threadIdx.x;
    float sum = 0.f, ss = 0.f;
    for (int i = tid * 4; i < GE; i += 4096) {
        float4 v = *(const float4*)(xp + i);
        sum += (v.x + v.y) + (v.z + v.w);
        ss  += (v.x * v.x + v.y * v.y) + (v.z * v.z + v.w * v.w);
    }
    #pragma unroll
    for (int o = 32; o; o >>= 1) {
        sum += __shfl_down(sum, o, 64);
        ss  += __shfl_down(ss, o, 64);
    }
    __shared__ float red[32];
    int wid = tid >> 6;
    if ((tid & 63) == 0) { red[wid] = sum; red[16 + wid] = ss; }
    __syncthreads();
    if (tid == 0) {
        sum = 0.f; ss = 0.f;
        #pragma unroll
        for (int i = 0; i < 16; ++i) { sum += red[i]; ss += red[16 + i]; }
        float mean = sum * (1.f / GE);
        float var  = ss * (1.f / GE) - mean * mean;
        stats[b * 32 + g] = make_float2(mean, rsqrtf(var + EPS));
    }
}

// ---------------- K2: weights fp32 -> bf16 ----------------
__global__ __launch_bounds__(256) void k_wcvt(const float* __restrict__ wq,
        const float* __restrict__ wk, const float* __restrict__ wv,
        const float* __restrict__ wo, short* __restrict__ wqkvb,
        short* __restrict__ wob) {
    int i = blockIdx.x * 256 + threadIdx.x;   // grid 1024 -> 262144
    if (i < 65536)       wqkvb[i] = f2bf(wq[i]);
    else if (i < 131072) wqkvb[i] = f2bf(wk[i - 65536]);
    else if (i < 196608) wqkvb[i] = f2bf(wv[i - 131072]);
    else                 wob[i - 196608] = f2bf(wo[i - 196608]);
}

// ---------------- K3: normalize + transpose -> xnT[b][n][c] bf16 ----------------
__global__ __launch_bounds__(256) void k_t(const float* __restrict__ x,
        const float* __restrict__ gs, const float* __restrict__ gb,
        const float2* __restrict__ stats, short* __restrict__ xnT) {
    __shared__ __align__(16) short lt[64][72];   // [n_local][c_local], pad 8
    int id = blockIdx.x;
    int b  = id >> 8;            // 2
    int ct = (id >> 6) & 3;      // 4 c-tiles of 64
    int nt = id & 63;            // 64 n-tiles of 64
    int c0 = ct * 64, n0 = nt * 64;
    int t = threadIdx.x;
    int cc = t >> 2;
    int c = c0 + cc;
    float2 st = stats[b * 32 + (c >> 3)];
    float sc = gs[c] * st.y;
    float bi = gb[c] - st.x * sc;
    const float* xp = x + (size_t)(b * C + c) * N + n0;
    #pragma unroll
    for (int it = 0; it < 4; ++it) {
        int f4 = (t & 3) + it * 4;
        float4 v = *(const float4*)(xp + f4 * 4);
        int nl = f4 * 4;
        lt[nl + 0][cc] = f2bf(v.x * sc + bi);
        lt[nl + 1][cc] = f2bf(v.y * sc + bi);
        lt[nl + 2][cc] = f2bf(v.z * sc + bi);
        lt[nl + 3][cc] = f2bf(v.w * sc + bi);
    }
    __syncthreads();
    int nl = t >> 2, seg = t & 3;
    short* op = xnT + (size_t)(b * N + n0 + nl) * C + c0 + seg * 16;
    s16x8 w0 = *(const s16x8*)&lt[nl][seg * 16];
    s16x8 w1 = *(const s16x8*)&lt[nl][seg * 16 + 8];
    *(s16x8*)op = w0;
    *(s16x8*)(op + 8) = w1;
}

// ---------------- K4: QKV projection, bf16 MFMA GEMM ----------------
__global__ __launch_bounds__(256) void k_qkv(const short* __restrict__ wqkvb,
        const short* __restrict__ xnT, const float* __restrict__ bq,
        const float* __restrict__ bk, const float* __restrict__ bv,
        short* __restrict__ qT, short* __restrict__ kT, short* __restrict__ vB) {
    __shared__ __align__(16) short lt[4][64][16];
    int nb = blockIdx.x, mb = blockIdx.y, b = blockIdx.z;
    int m0 = mb * 64, n0 = nb * 64;
    int wid = threadIdx.x >> 6, lane = threadIdx.x & 63;
    int lr = lane & 15, lg = lane >> 4;
    int mw = m0 + wid * 16;
    const short* ap_ = wqkvb + (mw + lr) * C + lg * 8;
    const short* bp_ = xnT + ((size_t)b * N + n0 + lr) * C + lg * 8;
    f32x4 acc[4] = {{0,0,0,0},{0,0,0,0},{0,0,0,0},{0,0,0,0}};
    #pragma unroll 4
    for (int k0 = 0; k0 < C; k0 += 32) {
        s16x8 a  = *(const s16x8*)(ap_ + k0);
        s16x8 x0 = *(const s16x8*)(bp_ + k0);
        s16x8 x1 = *(const s16x8*)(bp_ + 16 * C + k0);
        s16x8 x2 = *(const s16x8*)(bp_ + 32 * C + k0);
        s16x8 x3 = *(const s16x8*)(bp_ + 48 * C + k0);
        acc[0] = __builtin_amdgcn_mfma_f32_16x16x32_bf16(a, x0, acc[0], 0, 0, 0);
        acc[1] = __builtin_amdgcn_mfma_f32_16x16x32_bf16(a, x1, acc[1], 0, 0, 0);
        acc[2] = __builtin_amdgcn_mfma_f32_16x16x32_bf16(a, x2, acc[2], 0, 0, 0);
        acc[3] = __builtin_amdgcn_mfma_f32_16x16x32_bf16(a, x3, acc[3], 0, 0, 0);
    }
    int kind = mb >> 2;                  // 0=q 1=k 2=v
    const float* bias = kind == 0 ? bq : (kind == 1 ? bk : bv);
    int mloc = mw - kind * 256;
    float bvals[4];
    #pragma unroll
    for (int r = 0; r < 4; ++r) bvals[r] = bias[mloc + 4 * lg + r];
    int h = mloc >> 5;
    if (kind == 2) {
        short* vbase = vB + (size_t)((b * 8 + h) * 32) * N;
        #pragma unroll
        for (int f = 0; f < 4; ++f) {
            int n = n0 + f * 16 + lr;
            #pragma unroll
            for (int r = 0; r < 4; ++r) {
                int dd = (mloc & 31) + 4 * lg + r;
                vbase[(size_t)dd * N + n] = f2bf(acc[f][r] + bvals[r]);
            }
        }
    } else {
        short* dst = (kind == 0) ? qT : kT;
        #pragma unroll
        for (int f = 0; f < 4; ++f)
            #pragma unroll
            for (int r = 0; r < 4; ++r)
                lt[wid][f * 16 + lr][4 * lg + r] =
                    f2bf((acc[f][r] + bvals[r]) * QK_SCALE_E);
        int ln = lane;
        s16x8 w0 = *(const s16x8*)&lt[wid][ln][0];
        s16x8 w1 = *(const s16x8*)&lt[wid][ln][8];
        short* op = dst + ((size_t)(b * 8 + h) * N + n0 + ln) * 32 + (mloc & 16);
        *(s16x8*)op = w0;
        *(s16x8*)(op + 8) = w1;
    }
}

// ---------------- K5: MFMA flash attention, split-K=2, v_exp, XCD swizzle ----------
// NOTE: body is byte-identical to round 4's PASSING kernel except the rm/bh/i0
// swizzle derivation (one-variable change; rounds 3/5 showed prefetch+asm NaNs).
#define EXPB(d, s_) asm("v_exp_f32 %0, %1\n\ts_nop 0" : "=v"(d) : "v"(s_))

__global__ __launch_bounds__(256, 8) void k_attn(const short* __restrict__ qT,
        const short* __restrict__ kT, const short* __restrict__ vB,
        short* __restrict__ po0, short* __restrict__ po1,
        float* __restrict__ pl) {
    __shared__ __align__(16) short lo[4][16][40];
    // XCD-bijective swizzle: 1024 = 8 XCDs x 128. All 128 blocks landing on one
    // XCD share 2 bh values -> K/V working set 1 MB/XCD, resident in 4 MB L2.
    int xb  = blockIdx.x;
    int rm  = (xb & 7) * 128 + (xb >> 3);
    int bh  = rm >> 6;
    int wid = threadIdx.x >> 6;
    int i0  = (rm & 63) * 64 + wid * 16;
    int s   = blockIdx.y;          // split index
    int jb  = s * JL;
    int lane = threadIdx.x & 63;
    int lr = lane & 15, lg = lane >> 4;
    const short* qTb = qT + (size_t)bh * N * 32;
    const short* kTb = kT + (size_t)bh * N * 32;
    const short* vBb = vB + (size_t)bh * 32 * N;

    s16x8 aq = *(const s16x8*)(qTb + (i0 + lr) * 32 + lg * 8);
    s16x8 ones;
    #pragma unroll
    for (int e = 0; e < 8; ++e) ones[e] = (short)0x3F80;

    f32x4 o0 = {0,0,0,0}, o1 = {0,0,0,0}, lac = {0,0,0,0};
    const f32x4 zero = {0,0,0,0};

    const short* kp  = kTb + (size_t)(jb + lr) * 32 + lg * 8;
    const short* vp0 = vBb + (size_t)lr * N + jb + lg * 8;
    const short* vp1 = vBb + (size_t)(16 + lr) * N + jb + lg * 8;

    for (int j0 = 0; j0 < JL; j0 += 32) {
        s16x8 bk0 = *(const s16x8*)(kp + (size_t)j0 * 32);
        s16x8 bk1 = *(const s16x8*)(kp + (size_t)(j0 + 16) * 32);
        s16x8 bv0 = *(const s16x8*)(vp0 + j0);
        s16x8 bv1 = *(const s16x8*)(vp1 + j0);
        f32x4 s0 = __builtin_amdgcn_mfma_f32_16x16x32_bf16(bk0, aq, zero, 0, 0, 0);
        f32x4 s1 = __builtin_amdgcn_mfma_f32_16x16x32_bf16(bk1, aq, zero, 0, 0, 0);
        float e00, e01, e02, e03, e10, e11, e12, e13;
        EXPB(e00, s0[0]); EXPB(e01, s0[1]); EXPB(e02, s0[2]); EXPB(e03, s0[3]);
        EXPB(e10, s1[0]); EXPB(e11, s1[1]); EXPB(e12, s1[2]); EXPB(e13, s1[3]);
        unsigned w0, w1, w2, w3;
        asm("v_cvt_pk_bf16_f32 %0, %1, %2" : "=v"(w0) : "v"(e00), "v"(e01));
        asm("v_cvt_pk_bf16_f32 %0, %1, %2" : "=v"(w1) : "v"(e02), "v"(e03));
        asm("v_cvt_pk_bf16_f32 %0, %1, %2" : "=v"(w2) : "v"(e10), "v"(e11));
        asm("v_cvt_pk_bf16_f32 %0, %1, %2" : "=v"(w3) : "v"(e12), "v"(e13));
        asm("v_permlane32_swap_b32 %0, %1" : "+v"(w0), "+v"(w2));
        asm("v_permlane16_swap_b32 %0, %1" : "+v"(w0), "+v"(w2));
        asm("v_permlane32_swap_b32 %0, %1" : "+v"(w1), "+v"(w3));
        asm("v_permlane16_swap_b32 %0, %1" : "+v"(w1), "+v"(w3));
        union { int4 i4; s16x8 s8; } apu;
        apu.i4 = make_int4((int)w0, (int)w1, (int)w2, (int)w3);
        s16x8 ap = apu.s8;
        lac = __builtin_amdgcn_mfma_f32_16x16x32_bf16(ap, ones, lac, 0, 0, 0);
        o0  = __builtin_amdgcn_mfma_f32_16x16x32_bf16(ap, bv0, o0, 0, 0, 0);
        o1  = __builtin_amdgcn_mfma_f32_16x16x32_bf16(ap, bv1, o1, 0, 0, 0);
    }

    // unnormalized partial O (bf16) + row-sum l (fp32)
    #pragma unroll
    for (int r = 0; r < 4; ++r) {
        lo[wid][4 * lg + r][lr]      = f2bf(o0[r]);
        lo[wid][4 * lg + r][16 + lr] = f2bf(o1[r]);
    }
    if (lr == 0) {
        float* plp = pl + ((size_t)(s * 16 + bh)) * N + i0;
        #pragma unroll
        for (int r = 0; r < 4; ++r) plp[4 * lg + r] = lac[r];
    }
    short* pob = s ? po1 : po0;
    int il = lane >> 2, seg = lane & 3;
    s16x8 w = *(const s16x8*)&lo[wid][il][seg * 8];
    short* op = pob + ((size_t)bh * N + i0 + il) * 32 + seg * 8;
    *(s16x8*)op = w;
}

// ---------------- K5b: merge split partials in place -> po0 = O [bh][n][32] bf16 ----
__global__ __launch_bounds__(256) void k_merge(short* __restrict__ po0,
        const short* __restrict__ po1, const float* __restrict__ pl) {
    int idx = blockIdx.x * 256 + threadIdx.x;   // 262144: bh(16) x i(4096) x dseg(4)
    int dseg = idx & 3, i = (idx >> 2) & 4095, bh = idx >> 14;
    float l = pl[(size_t)bh * N + i] + pl[(size_t)(16 + bh) * N + i];
    float inv = 1.f / l;
    size_t off = ((size_t)bh * N + i) * 32 + dseg * 8;
    s16x8 a  = *(const s16x8*)(po0 + off);
    s16x8 c2 = *(const s16x8*)(po1 + off);
    s16x8 w;
    #pragma unroll
    for (int e = 0; e < 8; ++e)
        w[e] = f2bf((bf2f(a[e]) + bf2f(c2[e])) * inv);
    *(s16x8*)(po0 + off) = w;
}

// ---------------- K6: out projection + residual, bf16 MFMA GEMM ----------------
// B-operand read directly from merged O in [bh][n][32] layout.
__global__ __launch_bounds__(256) void k_out(const short* __restrict__ wob,
        const short* __restrict__ aoM, const float* __restrict__ bo,
        const float* __restrict__ x, float* __restrict__ out) {
    int nb = blockIdx.x, mb = blockIdx.y, b = blockIdx.z;
    int n0 = nb * 64;
    int wid = threadIdx.x >> 6, lane = threadIdx.x & 63;
    int lr = lane & 15, lg = lane >> 4;
    int mw = mb * 64 + wid * 16;
    const short* ap_ = wob + (mw + lr) * C + lg * 8;
    f32x4 acc[4] = {{0,0,0,0},{0,0,0,0},{0,0,0,0},{0,0,0,0}};
    #pragma unroll
    for (int h = 0; h < 8; ++h) {
        const short* bp = aoM + (((size_t)(b * 8 + h)) * N + n0 + lr) * 32 + lg * 8;
        s16x8 a  = *(const s16x8*)(ap_ + h * 32);
        s16x8 x0 = *(const s16x8*)(bp);
        s16x8 x1 = *(const s16x8*)(bp + 16 * 32);
        s16x8 x2 = *(const s16x8*)(bp + 32 * 32);
        s16x8 x3 = *(const s16x8*)(bp + 48 * 32);
        acc[0] = __builtin_amdgcn_mfma_f32_16x16x32_bf16(a, x0, acc[0], 0, 0, 0);
        acc[1] = __builtin_amdgcn_mfma_f32_16x16x32_bf16(a, x1, acc[1], 0, 0, 0);
        acc[2] = __builtin_amdgcn_mfma_f32_16x16x32_bf16(a, x2, acc[2], 0, 0, 0);
        acc[3] = __builtin_amdgcn_mfma_f32_16x16x32_bf16(a, x3, acc[3], 0, 0, 0);
    }
    float bvals[4];
    #pragma unroll
    for (int r = 0; r < 4; ++r) bvals[r] = bo[mw + 4 * lg + r];
    #pragma unroll
    for (int f = 0; f < 4; ++f) {
        int n = n0 + f * 16 + lr;
        #pragma unroll
        for (int r = 0; r < 4; ++r) {
            size_t idx = (size_t)(b * C + mw + 4 * lg + r) * N + n;
            out[idx] = acc[f][r] + bvals[r] + x[idx];
        }
    }
}

extern "C" void kernel_launch(void* const* d_in, const int* in_sizes, int n_in,
                              void* d_out, int out_size, void* d_ws, size_t ws_size,
                              hipStream_t stream) {
    const float* x  = (const float*)d_in[0];
    const float* gs = (const float*)d_in[1];
    const float* gb = (const float*)d_in[2];
    const float* wq = (const float*)d_in[3];
    const float* bq = (const float*)d_in[4];
    const float* wk = (const float*)d_in[5];
    const float* bk = (const float*)d_in[6];
    const float* wv = (const float*)d_in[7];
    const float* bv = (const float*)d_in[8];
    const float* wo = (const float*)d_in[9];
    const float* bo = (const float*)d_in[10];
    float* out = (float*)d_out;
    char* ws = (char*)d_ws;

    // Total ws usage: 0x14B0000 = 21.69 MB (< 22.02 MB proven safe in rounds 1-2).
    float2* stats = (float2*)(ws);              // 512 B
    short*  wqkvb = (short*)(ws + 0x1000);      // 384 KB, dead after k_qkv
    float*  pl    = (float*)(ws + 0x1000);      // 512 KB, overlays dead wqkvb
    short*  wob   = (short*)(ws + 0x81000);     // 128 KB
    short*  xnT   = (short*)(ws + 0xB0000);     // 4 MB [b][n][c], dead after k_qkv
    short*  po1   = (short*)(ws + 0xB0000);     // 4 MB, overlays dead xnT
    short*  qT    = (short*)(ws + 0x4B0000);    // 4 MB [bh][n][32]
    short*  kT    = (short*)(ws + 0x8B0000);    // 4 MB [bh][n][32]
    short*  vB    = (short*)(ws + 0xCB0000);    // 4 MB [bh][32][n]
    short*  po0   = (short*)(ws + 0x10B0000);   // 4 MB [bh][n][32]; merged O after k_merge

    k_stats<<<64, 1024, 0, stream>>>(x, stats);
    k_wcvt <<<1024, 256, 0, stream>>>(wq, wk, wv, wo, wqkvb, wob);
    k_t    <<<512, 256, 0, stream>>>(x, gs, gb, stats, xnT);
    k_qkv  <<<dim3(64, 12, 2), 256, 0, stream>>>(wqkvb, xnT, bq, bk, bv, qT, kT, vB);
    k_attn <<<dim3(1024, 2), 256, 0, stream>>>(qT, kT, vB, po0, po1, pl);
    k_merge<<<1024, 256, 0, stream>>>(po0, po1, pl);
    k_out  <<<dim3(64, 4, 2), 256, 0, stream>>>(wob, po0, bo, x, out);
}

// Round 7
// 182.593 us; speedup vs baseline: 1.6441x; 1.6441x over previous
//
#include <hip/hip_runtime.h>

#define C 256
#define N 4096
#define CPG 8
#define GE (CPG * N)
#define JL 2048               // keys per split (split-K = 2)

constexpr float EPS = 1e-5f;
// 32^-0.25 * sqrt(log2(e)) : folded so P = exp2(q'.k') = exp(q.k/sqrt(32))
constexpr float QK_SCALE_E = 0.50500979f;

typedef float f32x4 __attribute__((ext_vector_type(4)));
typedef short s16x8 __attribute__((ext_vector_type(8)));

__device__ __forceinline__ short f2bf(float f) {
    union { float f; unsigned u; } v; v.f = f;
    unsigned r = v.u + 0x7FFFu + ((v.u >> 16) & 1u);  // RNE
    return (short)(r >> 16);
}
__device__ __forceinline__ float bf2f(short s) {
    union { unsigned u; float f; } v; v.u = ((unsigned)(unsigned short)s) << 16;
    return v.f;
}

// ---------------- K1: GroupNorm stats (mean, rstd per (b,g)) ----------------
__global__ __launch_bounds__(1024) void k_stats(const float* __restrict__ x,
                                                float2* __restrict__ stats) {
    int b = blockIdx.x >> 5, g = blockIdx.x & 31;
    size_t base = (size_t)(b * C + g * CPG) * N;
    const float* xp = x + base;
    int tid = threadIdx.x;
    float sum = 0.f, ss = 0.f;
    for (int i = tid * 4; i < GE; i += 4096) {
        float4 v = *(const float4*)(xp + i);
        sum += (v.x + v.y) + (v.z + v.w);
        ss  += (v.x * v.x + v.y * v.y) + (v.z * v.z + v.w * v.w);
    }
    #pragma unroll
    for (int o = 32; o; o >>= 1) {
        sum += __shfl_down(sum, o, 64);
        ss  += __shfl_down(ss, o, 64);
    }
    __shared__ float red[32];
    int wid = tid >> 6;
    if ((tid & 63) == 0) { red[wid] = sum; red[16 + wid] = ss; }
    __syncthreads();
    if (tid == 0) {
        sum = 0.f; ss = 0.f;
        #pragma unroll
        for (int i = 0; i < 16; ++i) { sum += red[i]; ss += red[16 + i]; }
        float mean = sum * (1.f / GE);
        float var  = ss * (1.f / GE) - mean * mean;
        stats[b * 32 + g] = make_float2(mean, rsqrtf(var + EPS));
    }
}

// ---------------- K2: weights fp32 -> bf16 ----------------
__global__ __launch_bounds__(256) void k_wcvt(const float* __restrict__ wq,
        const float* __restrict__ wk, const float* __restrict__ wv,
        const float* __restrict__ wo, short* __restrict__ wqkvb,
        short* __restrict__ wob) {
    int i = blockIdx.x * 256 + threadIdx.x;   // grid 1024 -> 262144
    if (i < 65536)       wqkvb[i] = f2bf(wq[i]);
    else if (i < 131072) wqkvb[i] = f2bf(wk[i - 65536]);
    else if (i < 196608) wqkvb[i] = f2bf(wv[i - 131072]);
    else                 wob[i - 196608] = f2bf(wo[i - 196608]);
}

// ---------------- K3: normalize + transpose -> xnT[b][n][c] bf16 ----------------
__global__ __launch_bounds__(256) void k_t(const float* __restrict__ x,
        const float* __restrict__ gs, const float* __restrict__ gb,
        const float2* __restrict__ stats, short* __restrict__ xnT) {
    __shared__ __align__(16) short lt[64][72];   // [n_local][c_local], pad 8
    int id = blockIdx.x;
    int b  = id >> 8;            // 2
    int ct = (id >> 6) & 3;      // 4 c-tiles of 64
    int nt = id & 63;            // 64 n-tiles of 64
    int c0 = ct * 64, n0 = nt * 64;
    int t = threadIdx.x;
    int cc = t >> 2;
    int c = c0 + cc;
    float2 st = stats[b * 32 + (c >> 3)];
    float sc = gs[c] * st.y;
    float bi = gb[c] - st.x * sc;
    const float* xp = x + (size_t)(b * C + c) * N + n0;
    #pragma unroll
    for (int it = 0; it < 4; ++it) {
        int f4 = (t & 3) + it * 4;
        float4 v = *(const float4*)(xp + f4 * 4);
        int nl = f4 * 4;
        lt[nl + 0][cc] = f2bf(v.x * sc + bi);
        lt[nl + 1][cc] = f2bf(v.y * sc + bi);
        lt[nl + 2][cc] = f2bf(v.z * sc + bi);
        lt[nl + 3][cc] = f2bf(v.w * sc + bi);
    }
    __syncthreads();
    int nl = t >> 2, seg = t & 3;
    short* op = xnT + (size_t)(b * N + n0 + nl) * C + c0 + seg * 16;
    s16x8 w0 = *(const s16x8*)&lt[nl][seg * 16];
    s16x8 w1 = *(const s16x8*)&lt[nl][seg * 16 + 8];
    *(s16x8*)op = w0;
    *(s16x8*)(op + 8) = w1;
}

// ---------------- K4: QKV projection, bf16 MFMA GEMM ----------------
__global__ __launch_bounds__(256) void k_qkv(const short* __restrict__ wqkvb,
        const short* __restrict__ xnT, const float* __restrict__ bq,
        const float* __restrict__ bk, const float* __restrict__ bv,
        short* __restrict__ qT, short* __restrict__ kT, short* __restrict__ vB) {
    __shared__ __align__(16) short lt[4][64][16];
    int nb = blockIdx.x, mb = blockIdx.y, b = blockIdx.z;
    int m0 = mb * 64, n0 = nb * 64;
    int wid = threadIdx.x >> 6, lane = threadIdx.x & 63;
    int lr = lane & 15, lg = lane >> 4;
    int mw = m0 + wid * 16;
    const short* ap_ = wqkvb + (mw + lr) * C + lg * 8;
    const short* bp_ = xnT + ((size_t)b * N + n0 + lr) * C + lg * 8;
    f32x4 acc[4] = {{0,0,0,0},{0,0,0,0},{0,0,0,0},{0,0,0,0}};
    #pragma unroll 4
    for (int k0 = 0; k0 < C; k0 += 32) {
        s16x8 a  = *(const s16x8*)(ap_ + k0);
        s16x8 x0 = *(const s16x8*)(bp_ + k0);
        s16x8 x1 = *(const s16x8*)(bp_ + 16 * C + k0);
        s16x8 x2 = *(const s16x8*)(bp_ + 32 * C + k0);
        s16x8 x3 = *(const s16x8*)(bp_ + 48 * C + k0);
        acc[0] = __builtin_amdgcn_mfma_f32_16x16x32_bf16(a, x0, acc[0], 0, 0, 0);
        acc[1] = __builtin_amdgcn_mfma_f32_16x16x32_bf16(a, x1, acc[1], 0, 0, 0);
        acc[2] = __builtin_amdgcn_mfma_f32_16x16x32_bf16(a, x2, acc[2], 0, 0, 0);
        acc[3] = __builtin_amdgcn_mfma_f32_16x16x32_bf16(a, x3, acc[3], 0, 0, 0);
    }
    int kind = mb >> 2;                  // 0=q 1=k 2=v
    const float* bias = kind == 0 ? bq : (kind == 1 ? bk : bv);
    int mloc = mw - kind * 256;
    float bvals[4];
    #pragma unroll
    for (int r = 0; r < 4; ++r) bvals[r] = bias[mloc + 4 * lg + r];
    int h = mloc >> 5;
    if (kind == 2) {
        short* vbase = vB + (size_t)((b * 8 + h) * 32) * N;
        #pragma unroll
        for (int f = 0; f < 4; ++f) {
            int n = n0 + f * 16 + lr;
            #pragma unroll
            for (int r = 0; r < 4; ++r) {
                int dd = (mloc & 31) + 4 * lg + r;
                vbase[(size_t)dd * N + n] = f2bf(acc[f][r] + bvals[r]);
            }
        }
    } else {
        short* dst = (kind == 0) ? qT : kT;
        #pragma unroll
        for (int f = 0; f < 4; ++f)
            #pragma unroll
            for (int r = 0; r < 4; ++r)
                lt[wid][f * 16 + lr][4 * lg + r] =
                    f2bf((acc[f][r] + bvals[r]) * QK_SCALE_E);
        int ln = lane;
        s16x8 w0 = *(const s16x8*)&lt[wid][ln][0];
        s16x8 w1 = *(const s16x8*)&lt[wid][ln][8];
        short* op = dst + ((size_t)(b * 8 + h) * N + n0 + ln) * 32 + (mloc & 16);
        *(s16x8*)op = w0;
        *(s16x8*)(op + 8) = w1;
    }
}

// ---------------- K5: LDS-staged double-buffered flash attention ----------------
// Per block (4 waves): one bh, 64 q-rows, JL keys in 32 tiles of 64.
// K/V tile staged global->reg->LDS (issue-early/write-late), XOR-swizzled LDS.
#define EXPB(d, s_) asm("v_exp_f32 %0, %1\n\ts_nop 0" : "=v"(d) : "v"(s_))

#define TILE_BODY() do {                                                          \
    f32x4 s0 = __builtin_amdgcn_mfma_f32_16x16x32_bf16(bk0, aq, zero, 0, 0, 0);   \
    f32x4 s1 = __builtin_amdgcn_mfma_f32_16x16x32_bf16(bk1, aq, zero, 0, 0, 0);   \
    float e00, e01, e02, e03, e10, e11, e12, e13;                                 \
    EXPB(e00, s0[0]); EXPB(e01, s0[1]); EXPB(e02, s0[2]); EXPB(e03, s0[3]);       \
    EXPB(e10, s1[0]); EXPB(e11, s1[1]); EXPB(e12, s1[2]); EXPB(e13, s1[3]);       \
    unsigned w0, w1, w2, w3;                                                      \
    asm("v_cvt_pk_bf16_f32 %0, %1, %2" : "=v"(w0) : "v"(e00), "v"(e01));          \
    asm("v_cvt_pk_bf16_f32 %0, %1, %2" : "=v"(w1) : "v"(e02), "v"(e03));          \
    asm("v_cvt_pk_bf16_f32 %0, %1, %2" : "=v"(w2) : "v"(e10), "v"(e11));          \
    asm("v_cvt_pk_bf16_f32 %0, %1, %2" : "=v"(w3) : "v"(e12), "v"(e13));          \
    asm("v_permlane32_swap_b32 %0, %1" : "+v"(w0), "+v"(w2));                     \
    asm("v_permlane16_swap_b32 %0, %1" : "+v"(w0), "+v"(w2));                     \
    asm("v_permlane32_swap_b32 %0, %1" : "+v"(w1), "+v"(w3));                     \
    asm("v_permlane16_swap_b32 %0, %1" : "+v"(w1), "+v"(w3));                     \
    union { int4 i4; s16x8 s8; } apu;                                             \
    apu.i4 = make_int4((int)w0, (int)w1, (int)w2, (int)w3);                       \
    s16x8 ap = apu.s8;                                                            \
    lac = __builtin_amdgcn_mfma_f32_16x16x32_bf16(ap, ones, lac, 0, 0, 0);        \
    o0  = __builtin_amdgcn_mfma_f32_16x16x32_bf16(ap, bv0, o0, 0, 0, 0);          \
    o1  = __builtin_amdgcn_mfma_f32_16x16x32_bf16(ap, bv1, o1, 0, 0, 0);          \
} while (0)

__global__ __launch_bounds__(256, 8) void k_attn(const short* __restrict__ qT,
        const short* __restrict__ kT, const short* __restrict__ vB,
        short* __restrict__ po0, short* __restrict__ po1,
        float* __restrict__ pl) {
    // pool layout (shorts): [0..4095] K dbuf (2 x 64x32 swz), [4096..8191] V dbuf
    // (2 x 32x64 swz). Epilogue reuses [0..2559] for the output transpose.
    __shared__ __align__(16) short pool[8192];
    int xb  = blockIdx.x;
    int rm  = (xb & 7) * 128 + (xb >> 3);      // XCD-bijective swizzle (R6-proven)
    int bh  = rm >> 6;
    int wid = threadIdx.x >> 6;
    int i0  = (rm & 63) * 64 + wid * 16;
    int s   = blockIdx.y;
    int jb  = s * JL;
    int lane = threadIdx.x & 63;
    int lr = lane & 15, lg = lane >> 4;
    const short* qTb = qT + (size_t)bh * N * 32;
    const short* kTb = kT + (size_t)bh * N * 32;
    const short* vBb = vB + (size_t)bh * 32 * N;

    s16x8 aq = *(const s16x8*)(qTb + (i0 + lr) * 32 + lg * 8);
    s16x8 ones;
    #pragma unroll
    for (int e = 0; e < 8; ++e) ones[e] = (short)0x3F80;

    f32x4 o0 = {0,0,0,0}, o1 = {0,0,0,0}, lac = {0,0,0,0};
    const f32x4 zero = {0,0,0,0};

    // ---- staging addresses (per lane) ----
    int krow  = 16 * wid + (lane >> 2);        // 0..63  (tile-local K row)
    int kslot = lane & 3;                      // 16B slot within 64B row
    const short* kg = kTb + (size_t)(jb + krow) * 32 + kslot * 8;
    int kw_ofs = krow * 32 + ((kslot ^ (krow & 3)) * 8);      // swizzled LDS dst

    int vrow  = 8 * wid + (lane >> 3);         // 0..31  (d index)
    int vslot = lane & 7;                      // 16B slot within 128B row
    const short* vg = vBb + (size_t)vrow * N + jb + vslot * 8;
    int vw_ofs = vrow * 64 + ((vslot ^ (vrow & 7)) * 8);

    // ---- read-side fragment offsets (per lane, swizzle folded in) ----
    int kr_base = lr * 32 + ((lg ^ (lr & 3)) * 8);            // + kk*32
    int vr0 = lr * 64, vr1 = (16 + lr) * 64;
    int sw0 = ((0 + lg) ^ (lr & 7)) * 8;       // jc = 0
    int sw1 = ((4 + lg) ^ (lr & 7)) * 8;       // jc = 32

    // ---- prologue: stage tile 0 into buffer 0 ----
    {
        s16x8 kreg = *(const s16x8*)kg;
        s16x8 vreg = *(const s16x8*)vg;
        *(s16x8*)&pool[kw_ofs] = kreg;
        *(s16x8*)&pool[4096 + vw_ofs] = vreg;
    }
    __syncthreads();

    for (int t = 0; t < 32; ++t) {
        int p = t & 1;
        s16x8 nk, nv;
        if (t < 31) {                           // issue next-tile loads EARLY
            nk = *(const s16x8*)(kg + (t + 1) * 2048);
            nv = *(const s16x8*)(vg + (t + 1) * 64);
        }
        const short* lkp = &pool[p * 2048];
        const short* lvp = &pool[4096 + p * 2048];
        {   // jc = 0 (keys 0..31 of tile)
            s16x8 bk0 = *(const s16x8*)(lkp + kr_base);
            s16x8 bk1 = *(const s16x8*)(lkp + 512 + kr_base);
            s16x8 bv0 = *(const s16x8*)(lvp + vr0 + sw0);
            s16x8 bv1 = *(const s16x8*)(lvp + vr1 + sw0);
            TILE_BODY();
        }
        {   // jc = 32 (keys 32..63 of tile)
            s16x8 bk0 = *(const s16x8*)(lkp + 1024 + kr_base);
            s16x8 bk1 = *(const s16x8*)(lkp + 1536 + kr_base);
            s16x8 bv0 = *(const s16x8*)(lvp + vr0 + sw1);
            s16x8 bv1 = *(const s16x8*)(lvp + vr1 + sw1);
            TILE_BODY();
        }
        if (t < 31) {                           // write-late into other buffer
            int q = (t + 1) & 1;
            *(s16x8*)&pool[q * 2048 + kw_ofs] = nk;
            *(s16x8*)&pool[4096 + q * 2048 + vw_ofs] = nv;
        }
        __syncthreads();
    }

    // ---- epilogue: unnormalized partial O (bf16) + row-sum l (fp32) ----
    #pragma unroll
    for (int r = 0; r < 4; ++r) {
        pool[wid * 640 + (4 * lg + r) * 40 + lr]      = f2bf(o0[r]);
        pool[wid * 640 + (4 * lg + r) * 40 + 16 + lr] = f2bf(o1[r]);
    }
    if (lr == 0) {
        float* plp = pl + ((size_t)(s * 16 + bh)) * N + i0;
        #pragma unroll
        for (int r = 0; r < 4; ++r) plp[4 * lg + r] = lac[r];
    }
    short* pob = s ? po1 : po0;
    int il = lane >> 2, seg = lane & 3;
    s16x8 w = *(const s16x8*)&pool[wid * 640 + il * 40 + seg * 8];
    short* op = pob + ((size_t)bh * N + i0 + il) * 32 + seg * 8;
    *(s16x8*)op = w;
}

// ---------------- K5b: merge split partials in place -> po0 = O [bh][n][32] bf16 ----
__global__ __launch_bounds__(256) void k_merge(short* __restrict__ po0,
        const short* __restrict__ po1, const float* __restrict__ pl) {
    int idx = blockIdx.x * 256 + threadIdx.x;   // 262144: bh(16) x i(4096) x dseg(4)
    int dseg = idx & 3, i = (idx >> 2) & 4095, bh = idx >> 14;
    float l = pl[(size_t)bh * N + i] + pl[(size_t)(16 + bh) * N + i];
    float inv = 1.f / l;
    size_t off = ((size_t)bh * N + i) * 32 + dseg * 8;
    s16x8 a  = *(const s16x8*)(po0 + off);
    s16x8 c2 = *(const s16x8*)(po1 + off);
    s16x8 w;
    #pragma unroll
    for (int e = 0; e < 8; ++e)
        w[e] = f2bf((bf2f(a[e]) + bf2f(c2[e])) * inv);
    *(s16x8*)(po0 + off) = w;
}

// ---------------- K6: out projection + residual, bf16 MFMA GEMM ----------------
__global__ __launch_bounds__(256) void k_out(const short* __restrict__ wob,
        const short* __restrict__ aoM, const float* __restrict__ bo,
        const float* __restrict__ x, float* __restrict__ out) {
    int nb = blockIdx.x, mb = blockIdx.y, b = blockIdx.z;
    int n0 = nb * 64;
    int wid = threadIdx.x >> 6, lane = threadIdx.x & 63;
    int lr = lane & 15, lg = lane >> 4;
    int mw = mb * 64 + wid * 16;
    const short* ap_ = wob + (mw + lr) * C + lg * 8;
    f32x4 acc[4] = {{0,0,0,0},{0,0,0,0},{0,0,0,0},{0,0,0,0}};
    #pragma unroll
    for (int h = 0; h < 8; ++h) {
        const short* bp = aoM + (((size_t)(b * 8 + h)) * N + n0 + lr) * 32 + lg * 8;
        s16x8 a  = *(const s16x8*)(ap_ + h * 32);
        s16x8 x0 = *(const s16x8*)(bp);
        s16x8 x1 = *(const s16x8*)(bp + 16 * 32);
        s16x8 x2 = *(const s16x8*)(bp + 32 * 32);
        s16x8 x3 = *(const s16x8*)(bp + 48 * 32);
        acc[0] = __builtin_amdgcn_mfma_f32_16x16x32_bf16(a, x0, acc[0], 0, 0, 0);
        acc[1] = __builtin_amdgcn_mfma_f32_16x16x32_bf16(a, x1, acc[1], 0, 0, 0);
        acc[2] = __builtin_amdgcn_mfma_f32_16x16x32_bf16(a, x2, acc[2], 0, 0, 0);
        acc[3] = __builtin_amdgcn_mfma_f32_16x16x32_bf16(a, x3, acc[3], 0, 0, 0);
    }
    float bvals[4];
    #pragma unroll
    for (int r = 0; r < 4; ++r) bvals[r] = bo[mw + 4 * lg + r];
    #pragma unroll
    for (int f = 0; f < 4; ++f) {
        int n = n0 + f * 16 + lr;
        #pragma unroll
        for (int r = 0; r < 4; ++r) {
            size_t idx = (size_t)(b * C + mw + 4 * lg + r) * N + n;
            out[idx] = acc[f][r] + bvals[r] + x[idx];
        }
    }
}

extern "C" void kernel_launch(void* const* d_in, const int* in_sizes, int n_in,
                              void* d_out, int out_size, void* d_ws, size_t ws_size,
                              hipStream_t stream) {
    const float* x  = (const float*)d_in[0];
    const float* gs = (const float*)d_in[1];
    const float* gb = (const float*)d_in[2];
    const float* wq = (const float*)d_in[3];
    const float* bq = (const float*)d_in[4];
    const float* wk = (const float*)d_in[5];
    const float* bk = (const float*)d_in[6];
    const float* wv = (const float*)d_in[7];
    const float* bv = (const float*)d_in[8];
    const float* wo = (const float*)d_in[9];
    const float* bo = (const float*)d_in[10];
    float* out = (float*)d_out;
    char* ws = (char*)d_ws;

    // Total ws usage: 0x14B0000 = 21.69 MB (< 22.02 MB proven safe in rounds 1-2).
    float2* stats = (float2*)(ws);              // 512 B
    short*  wqkvb = (short*)(ws + 0x1000);      // 384 KB, dead after k_qkv
    float*  pl    = (float*)(ws + 0x1000);      // 512 KB, overlays dead wqkvb
    short*  wob   = (short*)(ws + 0x81000);     // 128 KB
    short*  xnT   = (short*)(ws + 0xB0000);     // 4 MB [b][n][c], dead after k_qkv
    short*  po1   = (short*)(ws + 0xB0000);     // 4 MB, overlays dead xnT
    short*  qT    = (short*)(ws + 0x4B0000);    // 4 MB [bh][n][32]
    short*  kT    = (short*)(ws + 0x8B0000);    // 4 MB [bh][n][32]
    short*  vB    = (short*)(ws + 0xCB0000);    // 4 MB [bh][32][n]
    short*  po0   = (short*)(ws + 0x10B0000);   // 4 MB [bh][n][32]; merged O after k_merge

    k_stats<<<64, 1024, 0, stream>>>(x, stats);
    k_wcvt <<<1024, 256, 0, stream>>>(wq, wk, wv, wo, wqkvb, wob);
    k_t    <<<512, 256, 0, stream>>>(x, gs, gb, stats, xnT);
    k_qkv  <<<dim3(64, 12, 2), 256, 0, stream>>>(wqkvb, xnT, bq, bk, bv, qT, kT, vB);
    k_attn <<<dim3(1024, 2), 256, 0, stream>>>(qT, kT, vB, po0, po1, pl);
    k_merge<<<1024, 256, 0, stream>>>(po0, po1, pl);
    k_out  <<<dim3(64, 4, 2), 256, 0, stream>>>(wob, po0, bo, x, out);
}

// Round 8
// 165.248 us; speedup vs baseline: 1.8167x; 1.1050x over previous
//
#include <hip/hip_runtime.h>

#define C 256
#define N 4096
#define CPG 8
#define GE (CPG * N)
#define JL 2048               // keys per split (split-K = 2)

constexpr float EPS = 1e-5f;
// 32^-0.25 * sqrt(log2(e)) : folded so P = exp2(q'.k') = exp(q.k/sqrt(32))
constexpr float QK_SCALE_E = 0.50500979f;

typedef float f32x4 __attribute__((ext_vector_type(4)));
typedef short s16x8 __attribute__((ext_vector_type(8)));

__device__ __forceinline__ short f2bf(float f) {
    union { float f; unsigned u; } v; v.f = f;
    unsigned r = v.u + 0x7FFFu + ((v.u >> 16) & 1u);  // RNE
    return (short)(r >> 16);
}
__device__ __forceinline__ float bf2f(short s) {
    union { unsigned u; float f; } v; v.u = ((unsigned)(unsigned short)s) << 16;
    return v.f;
}

// ---------------- K1: GroupNorm stats (mean, rstd per (b,g)) ----------------
__global__ __launch_bounds__(1024) void k_stats(const float* __restrict__ x,
                                                float2* __restrict__ stats) {
    int b = blockIdx.x >> 5, g = blockIdx.x & 31;
    size_t base = (size_t)(b * C + g * CPG) * N;
    const float* xp = x + base;
    int tid = threadIdx.x;
    float sum = 0.f, ss = 0.f;
    for (int i = tid * 4; i < GE; i += 4096) {
        float4 v = *(const float4*)(xp + i);
        sum += (v.x + v.y) + (v.z + v.w);
        ss  += (v.x * v.x + v.y * v.y) + (v.z * v.z + v.w * v.w);
    }
    #pragma unroll
    for (int o = 32; o; o >>= 1) {
        sum += __shfl_down(sum, o, 64);
        ss  += __shfl_down(ss, o, 64);
    }
    __shared__ float red[32];
    int wid = tid >> 6;
    if ((tid & 63) == 0) { red[wid] = sum; red[16 + wid] = ss; }
    __syncthreads();
    if (tid == 0) {
        sum = 0.f; ss = 0.f;
        #pragma unroll
        for (int i = 0; i < 16; ++i) { sum += red[i]; ss += red[16 + i]; }
        float mean = sum * (1.f / GE);
        float var  = ss * (1.f / GE) - mean * mean;
        stats[b * 32 + g] = make_float2(mean, rsqrtf(var + EPS));
    }
}

// ---------------- K2: weights fp32 -> bf16 ----------------
__global__ __launch_bounds__(256) void k_wcvt(const float* __restrict__ wq,
        const float* __restrict__ wk, const float* __restrict__ wv,
        const float* __restrict__ wo, short* __restrict__ wqkvb,
        short* __restrict__ wob) {
    int i = blockIdx.x * 256 + threadIdx.x;   // grid 1024 -> 262144
    if (i < 65536)       wqkvb[i] = f2bf(wq[i]);
    else if (i < 131072) wqkvb[i] = f2bf(wk[i - 65536]);
    else if (i < 196608) wqkvb[i] = f2bf(wv[i - 131072]);
    else                 wob[i - 196608] = f2bf(wo[i - 196608]);
}

// ---------------- K3: normalize + transpose -> xnT[b][n][c] bf16 ----------------
__global__ __launch_bounds__(256) void k_t(const float* __restrict__ x,
        const float* __restrict__ gs, const float* __restrict__ gb,
        const float2* __restrict__ stats, short* __restrict__ xnT) {
    __shared__ __align__(16) short lt[64][72];   // [n_local][c_local], pad 8
    int id = blockIdx.x;
    int b  = id >> 8;            // 2
    int ct = (id >> 6) & 3;      // 4 c-tiles of 64
    int nt = id & 63;            // 64 n-tiles of 64
    int c0 = ct * 64, n0 = nt * 64;
    int t = threadIdx.x;
    int cc = t >> 2;
    int c = c0 + cc;
    float2 st = stats[b * 32 + (c >> 3)];
    float sc = gs[c] * st.y;
    float bi = gb[c] - st.x * sc;
    const float* xp = x + (size_t)(b * C + c) * N + n0;
    #pragma unroll
    for (int it = 0; it < 4; ++it) {
        int f4 = (t & 3) + it * 4;
        float4 v = *(const float4*)(xp + f4 * 4);
        int nl = f4 * 4;
        lt[nl + 0][cc] = f2bf(v.x * sc + bi);
        lt[nl + 1][cc] = f2bf(v.y * sc + bi);
        lt[nl + 2][cc] = f2bf(v.z * sc + bi);
        lt[nl + 3][cc] = f2bf(v.w * sc + bi);
    }
    __syncthreads();
    int nl = t >> 2, seg = t & 3;
    short* op = xnT + (size_t)(b * N + n0 + nl) * C + c0 + seg * 16;
    s16x8 w0 = *(const s16x8*)&lt[nl][seg * 16];
    s16x8 w1 = *(const s16x8*)&lt[nl][seg * 16 + 8];
    *(s16x8*)op = w0;
    *(s16x8*)(op + 8) = w1;
}

// ---------------- K4: QKV projection, bf16 MFMA GEMM, LDS-staged B ----------------
// B-tile (64n x 256k, 32KB) staged once per block into XOR-swizzled LDS and shared
// by all 4 waves; 8 A-fragments (L2-resident weights) loaded upfront into regs.
__global__ __launch_bounds__(256) void k_qkv(const short* __restrict__ wqkvb,
        const short* __restrict__ xnT, const float* __restrict__ bq,
        const float* __restrict__ bk, const float* __restrict__ bv,
        short* __restrict__ qT, short* __restrict__ kT, short* __restrict__ vB) {
    __shared__ __align__(16) short bs[64 * 256];      // 32KB swizzled B-tile
    __shared__ __align__(16) short lt[4][64][16];     // 8KB epilogue transpose
    int nb = blockIdx.x, mb = blockIdx.y, b = blockIdx.z;
    int m0 = mb * 64, n0 = nb * 64;
    int t = threadIdx.x;
    int wid = t >> 6, lane = t & 63;
    int lr = lane & 15, lg = lane >> 4;
    int mw = m0 + wid * 16;

    // A fragments upfront (8 x 16B, breaks the per-k dependent chain)
    const short* ap_ = wqkvb + (mw + lr) * C + lg * 8;
    s16x8 af[8];
    #pragma unroll
    for (int kk = 0; kk < 8; ++kk)
        af[kk] = *(const s16x8*)(ap_ + kk * 32);

    // stage B: row gr = t>>2, 16B slots (t&3)+4i, LDS slot ^= (row&7)
    {
        int gr = t >> 2;
        const short* gp = xnT + ((size_t)b * N + n0 + gr) * C + (t & 3) * 8;
        #pragma unroll
        for (int i = 0; i < 8; ++i) {
            int sl = (t & 3) + 4 * i;
            s16x8 v = *(const s16x8*)(gp + 32 * i);
            *(s16x8*)&bs[gr * 256 + ((sl ^ (gr & 7)) * 8)] = v;
        }
    }
    __syncthreads();

    f32x4 acc[4] = {{0,0,0,0},{0,0,0,0},{0,0,0,0},{0,0,0,0}};
    #pragma unroll
    for (int kk = 0; kk < 8; ++kk) {
        int sb = kk * 4;                       // slot base = k0/8
        #pragma unroll
        for (int f = 0; f < 4; ++f) {
            int row = f * 16 + lr;
            s16x8 xf = *(const s16x8*)&bs[row * 256 + (((sb + lg) ^ (lr & 7)) * 8)];
            acc[f] = __builtin_amdgcn_mfma_f32_16x16x32_bf16(af[kk], xf, acc[f], 0, 0, 0);
        }
    }

    int kind = mb >> 2;                  // 0=q 1=k 2=v
    const float* bias = kind == 0 ? bq : (kind == 1 ? bk : bv);
    int mloc = mw - kind * 256;
    float bvals[4];
    #pragma unroll
    for (int r = 0; r < 4; ++r) bvals[r] = bias[mloc + 4 * lg + r];
    int h = mloc >> 5;
    if (kind == 2) {
        short* vbase = vB + (size_t)((b * 8 + h) * 32) * N;
        #pragma unroll
        for (int f = 0; f < 4; ++f) {
            int n = n0 + f * 16 + lr;
            #pragma unroll
            for (int r = 0; r < 4; ++r) {
                int dd = (mloc & 31) + 4 * lg + r;
                vbase[(size_t)dd * N + n] = f2bf(acc[f][r] + bvals[r]);
            }
        }
    } else {
        short* dst = (kind == 0) ? qT : kT;
        #pragma unroll
        for (int f = 0; f < 4; ++f)
            #pragma unroll
            for (int r = 0; r < 4; ++r)
                lt[wid][f * 16 + lr][4 * lg + r] =
                    f2bf((acc[f][r] + bvals[r]) * QK_SCALE_E);
        int ln = lane;
        s16x8 w0 = *(const s16x8*)&lt[wid][ln][0];
        s16x8 w1 = *(const s16x8*)&lt[wid][ln][8];
        short* op = dst + ((size_t)(b * 8 + h) * N + n0 + ln) * 32 + (mloc & 16);
        *(s16x8*)op = w0;
        *(s16x8*)(op + 8) = w1;
    }
}

// ---------------- K5: LDS-staged double-buffered flash attention (R7-proven) ------
#define EXPB(d, s_) asm("v_exp_f32 %0, %1\n\ts_nop 0" : "=v"(d) : "v"(s_))

#define TILE_BODY() do {                                                          \
    f32x4 s0 = __builtin_amdgcn_mfma_f32_16x16x32_bf16(bk0, aq, zero, 0, 0, 0);   \
    f32x4 s1 = __builtin_amdgcn_mfma_f32_16x16x32_bf16(bk1, aq, zero, 0, 0, 0);   \
    float e00, e01, e02, e03, e10, e11, e12, e13;                                 \
    EXPB(e00, s0[0]); EXPB(e01, s0[1]); EXPB(e02, s0[2]); EXPB(e03, s0[3]);       \
    EXPB(e10, s1[0]); EXPB(e11, s1[1]); EXPB(e12, s1[2]); EXPB(e13, s1[3]);       \
    unsigned w0, w1, w2, w3;                                                      \
    asm("v_cvt_pk_bf16_f32 %0, %1, %2" : "=v"(w0) : "v"(e00), "v"(e01));          \
    asm("v_cvt_pk_bf16_f32 %0, %1, %2" : "=v"(w1) : "v"(e02), "v"(e03));          \
    asm("v_cvt_pk_bf16_f32 %0, %1, %2" : "=v"(w2) : "v"(e10), "v"(e11));          \
    asm("v_cvt_pk_bf16_f32 %0, %1, %2" : "=v"(w3) : "v"(e12), "v"(e13));          \
    asm("v_permlane32_swap_b32 %0, %1" : "+v"(w0), "+v"(w2));                     \
    asm("v_permlane16_swap_b32 %0, %1" : "+v"(w0), "+v"(w2));                     \
    asm("v_permlane32_swap_b32 %0, %1" : "+v"(w1), "+v"(w3));                     \
    asm("v_permlane16_swap_b32 %0, %1" : "+v"(w1), "+v"(w3));                     \
    union { int4 i4; s16x8 s8; } apu;                                             \
    apu.i4 = make_int4((int)w0, (int)w1, (int)w2, (int)w3);                       \
    s16x8 ap = apu.s8;                                                            \
    lac = __builtin_amdgcn_mfma_f32_16x16x32_bf16(ap, ones, lac, 0, 0, 0);        \
    o0  = __builtin_amdgcn_mfma_f32_16x16x32_bf16(ap, bv0, o0, 0, 0, 0);          \
    o1  = __builtin_amdgcn_mfma_f32_16x16x32_bf16(ap, bv1, o1, 0, 0, 0);          \
} while (0)

__global__ __launch_bounds__(256, 8) void k_attn(const short* __restrict__ qT,
        const short* __restrict__ kT, const short* __restrict__ vB,
        short* __restrict__ po0, short* __restrict__ po1,
        float* __restrict__ pl) {
    __shared__ __align__(16) short pool[8192];
    int xb  = blockIdx.x;
    int rm  = (xb & 7) * 128 + (xb >> 3);      // XCD-bijective swizzle
    int bh  = rm >> 6;
    int wid = threadIdx.x >> 6;
    int i0  = (rm & 63) * 64 + wid * 16;
    int s   = blockIdx.y;
    int jb  = s * JL;
    int lane = threadIdx.x & 63;
    int lr = lane & 15, lg = lane >> 4;
    const short* qTb = qT + (size_t)bh * N * 32;
    const short* kTb = kT + (size_t)bh * N * 32;
    const short* vBb = vB + (size_t)bh * 32 * N;

    s16x8 aq = *(const s16x8*)(qTb + (i0 + lr) * 32 + lg * 8);
    s16x8 ones;
    #pragma unroll
    for (int e = 0; e < 8; ++e) ones[e] = (short)0x3F80;

    f32x4 o0 = {0,0,0,0}, o1 = {0,0,0,0}, lac = {0,0,0,0};
    const f32x4 zero = {0,0,0,0};

    int krow  = 16 * wid + (lane >> 2);
    int kslot = lane & 3;
    const short* kg = kTb + (size_t)(jb + krow) * 32 + kslot * 8;
    int kw_ofs = krow * 32 + ((kslot ^ (krow & 3)) * 8);

    int vrow  = 8 * wid + (lane >> 3);
    int vslot = lane & 7;
    const short* vg = vBb + (size_t)vrow * N + jb + vslot * 8;
    int vw_ofs = vrow * 64 + ((vslot ^ (vrow & 7)) * 8);

    int kr_base = lr * 32 + ((lg ^ (lr & 3)) * 8);
    int vr0 = lr * 64, vr1 = (16 + lr) * 64;
    int sw0 = ((0 + lg) ^ (lr & 7)) * 8;
    int sw1 = ((4 + lg) ^ (lr & 7)) * 8;

    {
        s16x8 kreg = *(const s16x8*)kg;
        s16x8 vreg = *(const s16x8*)vg;
        *(s16x8*)&pool[kw_ofs] = kreg;
        *(s16x8*)&pool[4096 + vw_ofs] = vreg;
    }
    __syncthreads();

    for (int t = 0; t < 32; ++t) {
        int p = t & 1;
        s16x8 nk, nv;
        if (t < 31) {
            nk = *(const s16x8*)(kg + (t + 1) * 2048);
            nv = *(const s16x8*)(vg + (t + 1) * 64);
        }
        const short* lkp = &pool[p * 2048];
        const short* lvp = &pool[4096 + p * 2048];
        {
            s16x8 bk0 = *(const s16x8*)(lkp + kr_base);
            s16x8 bk1 = *(const s16x8*)(lkp + 512 + kr_base);
            s16x8 bv0 = *(const s16x8*)(lvp + vr0 + sw0);
            s16x8 bv1 = *(const s16x8*)(lvp + vr1 + sw0);
            TILE_BODY();
        }
        {
            s16x8 bk0 = *(const s16x8*)(lkp + 1024 + kr_base);
            s16x8 bk1 = *(const s16x8*)(lkp + 1536 + kr_base);
            s16x8 bv0 = *(const s16x8*)(lvp + vr0 + sw1);
            s16x8 bv1 = *(const s16x8*)(lvp + vr1 + sw1);
            TILE_BODY();
        }
        if (t < 31) {
            int q = (t + 1) & 1;
            *(s16x8*)&pool[q * 2048 + kw_ofs] = nk;
            *(s16x8*)&pool[4096 + q * 2048 + vw_ofs] = nv;
        }
        __syncthreads();
    }

    #pragma unroll
    for (int r = 0; r < 4; ++r) {
        pool[wid * 640 + (4 * lg + r) * 40 + lr]      = f2bf(o0[r]);
        pool[wid * 640 + (4 * lg + r) * 40 + 16 + lr] = f2bf(o1[r]);
    }
    if (lr == 0) {
        float* plp = pl + ((size_t)(s * 16 + bh)) * N + i0;
        #pragma unroll
        for (int r = 0; r < 4; ++r) plp[4 * lg + r] = lac[r];
    }
    short* pob = s ? po1 : po0;
    int il = lane >> 2, seg = lane & 3;
    s16x8 w = *(const s16x8*)&pool[wid * 640 + il * 40 + seg * 8];
    short* op = pob + ((size_t)bh * N + i0 + il) * 32 + seg * 8;
    *(s16x8*)op = w;
}

// ---------------- K6: out projection + residual; merge folded into LDS staging ----
// Stages (po0+po1)*inv for all 8 heads (64n x 32d each, 32KB swizzled), then
// MFMA against upfront-loaded wob fragments. Replaces the separate k_merge pass.
__global__ __launch_bounds__(256) void k_out(const short* __restrict__ wob,
        const short* __restrict__ po0, const short* __restrict__ po1,
        const float* __restrict__ pl, const float* __restrict__ bo,
        const float* __restrict__ x, float* __restrict__ out) {
    __shared__ __align__(16) short bs[8 * 64 * 32];   // 32KB: 8 h-tiles swizzled
    int nb = blockIdx.x, mb = blockIdx.y, b = blockIdx.z;
    int n0 = nb * 64;
    int t = threadIdx.x;
    int wid = t >> 6, lane = t & 63;
    int lr = lane & 15, lg = lane >> 4;
    int mw = mb * 64 + wid * 16;

    const short* ap_ = wob + (mw + lr) * C + lg * 8;
    s16x8 af[8];
    #pragma unroll
    for (int h = 0; h < 8; ++h) af[h] = *(const s16x8*)(ap_ + h * 32);

    // stage + merge + normalize: thread t covers h = t>>5, chunks (t&31)+32i
    {
        int h = t >> 5, idx = t & 31;
        size_t rb = ((size_t)(b * 8 + h)) * N + n0;
        const short* g0 = po0 + rb * 32;
        const short* g1 = po1 + rb * 32;
        const float* pl0 = pl + rb;
        const float* pl1 = pl + (size_t)16 * N * 16 / 16 * 1;  // placeholder, fixed below
        pl1 = pl + ((size_t)(16 + b * 8 + h)) * N + n0;
        #pragma unroll
        for (int i = 0; i < 8; ++i) {
            int chunk = idx + 32 * i;
            int r = chunk >> 2, sl = chunk & 3;
            s16x8 v0 = *(const s16x8*)(g0 + r * 32 + sl * 8);
            s16x8 v1 = *(const s16x8*)(g1 + r * 32 + sl * 8);
            float inv = 1.f / (pl0[r] + pl1[r]);
            s16x8 w;
            #pragma unroll
            for (int e = 0; e < 8; ++e)
                w[e] = f2bf((bf2f(v0[e]) + bf2f(v1[e])) * inv);
            *(s16x8*)&bs[h * 2048 + r * 32 + ((sl ^ (r & 3)) * 8)] = w;
        }
    }
    __syncthreads();

    f32x4 acc[4] = {{0,0,0,0},{0,0,0,0},{0,0,0,0},{0,0,0,0}};
    #pragma unroll
    for (int h = 0; h < 8; ++h) {
        #pragma unroll
        for (int f = 0; f < 4; ++f) {
            int row = f * 16 + lr;
            s16x8 xf = *(const s16x8*)&bs[h * 2048 + row * 32 + ((lg ^ (lr & 3)) * 8)];
            acc[f] = __builtin_amdgcn_mfma_f32_16x16x32_bf16(af[h], xf, acc[f], 0, 0, 0);
        }
    }

    float bvals[4];
    #pragma unroll
    for (int r = 0; r < 4; ++r) bvals[r] = bo[mw + 4 * lg + r];
    #pragma unroll
    for (int f = 0; f < 4; ++f) {
        int n = n0 + f * 16 + lr;
        #pragma unroll
        for (int r = 0; r < 4; ++r) {
            size_t idx = (size_t)(b * C + mw + 4 * lg + r) * N + n;
            out[idx] = acc[f][r] + bvals[r] + x[idx];
        }
    }
}

extern "C" void kernel_launch(void* const* d_in, const int* in_sizes, int n_in,
                              void* d_out, int out_size, void* d_ws, size_t ws_size,
                              hipStream_t stream) {
    const float* x  = (const float*)d_in[0];
    const float* gs = (const float*)d_in[1];
    const float* gb = (const float*)d_in[2];
    const float* wq = (const float*)d_in[3];
    const float* bq = (const float*)d_in[4];
    const float* wk = (const float*)d_in[5];
    const float* bk = (const float*)d_in[6];
    const float* wv = (const float*)d_in[7];
    const float* bv = (const float*)d_in[8];
    const float* wo = (const float*)d_in[9];
    const float* bo = (const float*)d_in[10];
    float* out = (float*)d_out;
    char* ws = (char*)d_ws;

    // Total ws usage: 0x14B0000 = 21.69 MB (< 22.02 MB proven safe in rounds 1-2).
    float2* stats = (float2*)(ws);              // 512 B
    short*  wqkvb = (short*)(ws + 0x1000);      // 384 KB, dead after k_qkv
    float*  pl    = (float*)(ws + 0x1000);      // 512 KB, overlays dead wqkvb
    short*  wob   = (short*)(ws + 0x81000);     // 128 KB
    short*  xnT   = (short*)(ws + 0xB0000);     // 4 MB [b][n][c], dead after k_qkv
    short*  po1   = (short*)(ws + 0xB0000);     // 4 MB, overlays dead xnT
    short*  qT    = (short*)(ws + 0x4B0000);    // 4 MB [bh][n][32]
    short*  kT    = (short*)(ws + 0x8B0000);    // 4 MB [bh][n][32]
    short*  vB    = (short*)(ws + 0xCB0000);    // 4 MB [bh][32][n]
    short*  po0   = (short*)(ws + 0x10B0000);   // 4 MB [bh][n][32]

    k_stats<<<64, 1024, 0, stream>>>(x, stats);
    k_wcvt <<<1024, 256, 0, stream>>>(wq, wk, wv, wo, wqkvb, wob);
    k_t    <<<512, 256, 0, stream>>>(x, gs, gb, stats, xnT);
    k_qkv  <<<dim3(64, 12, 2), 256, 0, stream>>>(wqkvb, xnT, bq, bk, bv, qT, kT, vB);
    k_attn <<<dim3(1024, 2), 256, 0, stream>>>(qT, kT, vB, po0, po1, pl);
    k_out  <<<dim3(64, 4, 2), 256, 0, stream>>>(wob, po0, po1, pl, bo, x, out);
}

// Round 9
// 158.807 us; speedup vs baseline: 1.8904x; 1.0406x over previous
//
#include <hip/hip_runtime.h>

#define C 256
#define N 4096
#define CPG 8
#define GE (CPG * N)
#define JL 2048               // keys per split (split-K = 2)

constexpr float EPS = 1e-5f;
// 32^-0.25 * sqrt(log2(e)) : folded so P = exp2(q'.k') = exp(q.k/sqrt(32))
constexpr float QK_SCALE_E = 0.50500979f;

typedef float f32x4 __attribute__((ext_vector_type(4)));
typedef short s16x8 __attribute__((ext_vector_type(8)));

__device__ __forceinline__ short f2bf(float f) {
    union { float f; unsigned u; } v; v.f = f;
    unsigned r = v.u + 0x7FFFu + ((v.u >> 16) & 1u);  // RNE
    return (short)(r >> 16);
}
__device__ __forceinline__ float bf2f(short s) {
    union { unsigned u; float f; } v; v.u = ((unsigned)(unsigned short)s) << 16;
    return v.f;
}

// ---------------- K1: GroupNorm partial stats (4 n-chunks per (b,g)) ----------------
__global__ __launch_bounds__(256) void k_stats(const float* __restrict__ x,
                                               float2* __restrict__ partials) {
    int q = blockIdx.x & 3, g = (blockIdx.x >> 2) & 31, b = blockIdx.x >> 7;
    size_t base = (size_t)(b * C + g * CPG) * N + q * (GE / 4);
    const float* xp = x + base;
    int tid = threadIdx.x;
    float sum = 0.f, ss = 0.f;
    for (int i = tid * 4; i < GE / 4; i += 1024) {
        float4 v = *(const float4*)(xp + i);
        sum += (v.x + v.y) + (v.z + v.w);
        ss  += (v.x * v.x + v.y * v.y) + (v.z * v.z + v.w * v.w);
    }
    #pragma unroll
    for (int o = 32; o; o >>= 1) {
        sum += __shfl_down(sum, o, 64);
        ss  += __shfl_down(ss, o, 64);
    }
    __shared__ float red[8];
    int wid = tid >> 6;
    if ((tid & 63) == 0) { red[wid] = sum; red[4 + wid] = ss; }
    __syncthreads();
    if (tid == 0) {
        sum = red[0] + red[1] + red[2] + red[3];
        ss  = red[4] + red[5] + red[6] + red[7];
        partials[(b * 32 + g) * 4 + q] = make_float2(sum, ss);
    }
}

// ---------------- K2: weights fp32 -> bf16 ----------------
__global__ __launch_bounds__(256) void k_wcvt(const float* __restrict__ wq,
        const float* __restrict__ wk, const float* __restrict__ wv,
        const float* __restrict__ wo, short* __restrict__ wqkvb,
        short* __restrict__ wob) {
    int i = blockIdx.x * 256 + threadIdx.x;   // grid 1024 -> 262144
    if (i < 65536)       wqkvb[i] = f2bf(wq[i]);
    else if (i < 131072) wqkvb[i] = f2bf(wk[i - 65536]);
    else if (i < 196608) wqkvb[i] = f2bf(wv[i - 131072]);
    else                 wob[i - 196608] = f2bf(wo[i - 196608]);
}

// ---------------- K3: normalize + transpose -> xnT[b][n][c] bf16 ----------------
__global__ __launch_bounds__(256) void k_t(const float* __restrict__ x,
        const float* __restrict__ gs, const float* __restrict__ gb,
        const float2* __restrict__ partials, short* __restrict__ xnT) {
    __shared__ __align__(16) short lt[64][72];   // [n_local][c_local], pad 8
    int id = blockIdx.x;
    int b  = id >> 8;            // 2
    int ct = (id >> 6) & 3;      // 4 c-tiles of 64
    int nt = id & 63;            // 64 n-tiles of 64
    int c0 = ct * 64, n0 = nt * 64;
    int t = threadIdx.x;
    int cc = t >> 2;
    int c = c0 + cc;
    int bg = b * 32 + (c >> 3);
    float2 p0 = partials[bg * 4 + 0], p1 = partials[bg * 4 + 1];
    float2 p2 = partials[bg * 4 + 2], p3 = partials[bg * 4 + 3];
    float sum = (p0.x + p1.x) + (p2.x + p3.x);
    float ss  = (p0.y + p1.y) + (p2.y + p3.y);
    float mean = sum * (1.f / GE);
    float var  = ss * (1.f / GE) - mean * mean;
    float rstd = rsqrtf(var + EPS);
    float sc = gs[c] * rstd;
    float bi = gb[c] - mean * sc;
    const float* xp = x + (size_t)(b * C + c) * N + n0;
    #pragma unroll
    for (int it = 0; it < 4; ++it) {
        int f4 = (t & 3) + it * 4;
        float4 v = *(const float4*)(xp + f4 * 4);
        int nl = f4 * 4;
        lt[nl + 0][cc] = f2bf(v.x * sc + bi);
        lt[nl + 1][cc] = f2bf(v.y * sc + bi);
        lt[nl + 2][cc] = f2bf(v.z * sc + bi);
        lt[nl + 3][cc] = f2bf(v.w * sc + bi);
    }
    __syncthreads();
    int nl = t >> 2, seg = t & 3;
    short* op = xnT + (size_t)(b * N + n0 + nl) * C + c0 + seg * 16;
    s16x8 w0 = *(const s16x8*)&lt[nl][seg * 16];
    s16x8 w1 = *(const s16x8*)&lt[nl][seg * 16 + 8];
    *(s16x8*)op = w0;
    *(s16x8*)(op + 8) = w1;
}

// ---------------- K4: QKV projection, bf16 MFMA GEMM, LDS-staged B ----------------
// grid (12,64,2): the 12 m-blocks sharing a B-tile are dispatch-adjacent.
// V epilogue transposed through LDS -> coalesced 16B stores (was 2B scatter).
__global__ __launch_bounds__(256) void k_qkv(const short* __restrict__ wqkvb,
        const short* __restrict__ xnT, const float* __restrict__ bq,
        const float* __restrict__ bk, const float* __restrict__ bv,
        short* __restrict__ qT, short* __restrict__ kT, short* __restrict__ vB) {
    __shared__ __align__(16) short bs[64 * 256];      // 32KB swizzled B-tile
    __shared__ __align__(16) short lt[4][64][16];     // 8KB epilogue scratch
    int mb = blockIdx.x, nb = blockIdx.y, b = blockIdx.z;
    int m0 = mb * 64, n0 = nb * 64;
    int t = threadIdx.x;
    int wid = t >> 6, lane = t & 63;
    int lr = lane & 15, lg = lane >> 4;
    int mw = m0 + wid * 16;

    const short* ap_ = wqkvb + (mw + lr) * C + lg * 8;
    s16x8 af[8];
    #pragma unroll
    for (int kk = 0; kk < 8; ++kk)
        af[kk] = *(const s16x8*)(ap_ + kk * 32);

    {
        int gr = t >> 2;
        const short* gp = xnT + ((size_t)b * N + n0 + gr) * C + (t & 3) * 8;
        #pragma unroll
        for (int i = 0; i < 8; ++i) {
            int sl = (t & 3) + 4 * i;
            s16x8 v = *(const s16x8*)(gp + 32 * i);
            *(s16x8*)&bs[gr * 256 + ((sl ^ (gr & 7)) * 8)] = v;
        }
    }
    __syncthreads();

    f32x4 acc[4] = {{0,0,0,0},{0,0,0,0},{0,0,0,0},{0,0,0,0}};
    #pragma unroll
    for (int kk = 0; kk < 8; ++kk) {
        int sb = kk * 4;
        #pragma unroll
        for (int f = 0; f < 4; ++f) {
            int row = f * 16 + lr;
            s16x8 xf = *(const s16x8*)&bs[row * 256 + (((sb + lg) ^ (lr & 7)) * 8)];
            acc[f] = __builtin_amdgcn_mfma_f32_16x16x32_bf16(af[kk], xf, acc[f], 0, 0, 0);
        }
    }

    int kind = mb >> 2;                  // 0=q 1=k 2=v
    const float* bias = kind == 0 ? bq : (kind == 1 ? bk : bv);
    int mloc = mw - kind * 256;
    float bvals[4];
    #pragma unroll
    for (int r = 0; r < 4; ++r) bvals[r] = bias[mloc + 4 * lg + r];
    int h = mloc >> 5;
    if (kind == 2) {
        // transpose 64ch x 64n through swizzled LDS, then coalesced 16B stores
        short (*vt)[64] = (short(*)[64])lt;
        #pragma unroll
        for (int f = 0; f < 4; ++f)
            #pragma unroll
            for (int r = 0; r < 4; ++r) {
                int rl = wid * 16 + 4 * lg + r;     // channel-local 0..63
                int cn = f * 16 + lr;               // n-local 0..63
                int sl = cn >> 3, off = cn & 7;
                vt[rl][((sl ^ (rl & 7)) * 8) + off] = f2bf(acc[f][r] + bvals[r]);
            }
        __syncthreads();
        int mlocB = mb * 64 - 512;                  // block channel base
        int h0 = mlocB >> 5;
        int rr = t >> 2, sl = t & 3;
        int h2 = h0 + (rr >> 5), dd = rr & 31;
        short* vdst = vB + ((size_t)((b * 8 + h2) * 32 + dd)) * N + n0;
        s16x8 w0v = *(const s16x8*)&vt[rr][(sl ^ (rr & 7)) * 8];
        s16x8 w1v = *(const s16x8*)&vt[rr][((sl + 4) ^ (rr & 7)) * 8];
        *(s16x8*)(vdst + sl * 8) = w0v;
        *(s16x8*)(vdst + (sl + 4) * 8) = w1v;
    } else {
        short* dst = (kind == 0) ? qT : kT;
        #pragma unroll
        for (int f = 0; f < 4; ++f)
            #pragma unroll
            for (int r = 0; r < 4; ++r)
                lt[wid][f * 16 + lr][4 * lg + r] =
                    f2bf((acc[f][r] + bvals[r]) * QK_SCALE_E);
        int ln = lane;
        s16x8 w0 = *(const s16x8*)&lt[wid][ln][0];
        s16x8 w1 = *(const s16x8*)&lt[wid][ln][8];
        short* op = dst + ((size_t)(b * 8 + h) * N + n0 + ln) * 32 + (mloc & 16);
        *(s16x8*)op = w0;
        *(s16x8*)(op + 8) = w1;
    }
}

// ---------------- K5: LDS-staged double-buffered flash attention (R7-proven) ------
#define EXPB(d, s_) asm("v_exp_f32 %0, %1\n\ts_nop 0" : "=v"(d) : "v"(s_))

#define TILE_BODY() do {                                                          \
    f32x4 s0 = __builtin_amdgcn_mfma_f32_16x16x32_bf16(bk0, aq, zero, 0, 0, 0);   \
    f32x4 s1 = __builtin_amdgcn_mfma_f32_16x16x32_bf16(bk1, aq, zero, 0, 0, 0);   \
    float e00, e01, e02, e03, e10, e11, e12, e13;                                 \
    EXPB(e00, s0[0]); EXPB(e01, s0[1]); EXPB(e02, s0[2]); EXPB(e03, s0[3]);       \
    EXPB(e10, s1[0]); EXPB(e11, s1[1]); EXPB(e12, s1[2]); EXPB(e13, s1[3]);       \
    unsigned w0, w1, w2, w3;                                                      \
    asm("v_cvt_pk_bf16_f32 %0, %1, %2" : "=v"(w0) : "v"(e00), "v"(e01));          \
    asm("v_cvt_pk_bf16_f32 %0, %1, %2" : "=v"(w1) : "v"(e02), "v"(e03));          \
    asm("v_cvt_pk_bf16_f32 %0, %1, %2" : "=v"(w2) : "v"(e10), "v"(e11));          \
    asm("v_cvt_pk_bf16_f32 %0, %1, %2" : "=v"(w3) : "v"(e12), "v"(e13));          \
    asm("v_permlane32_swap_b32 %0, %1" : "+v"(w0), "+v"(w2));                     \
    asm("v_permlane16_swap_b32 %0, %1" : "+v"(w0), "+v"(w2));                     \
    asm("v_permlane32_swap_b32 %0, %1" : "+v"(w1), "+v"(w3));                     \
    asm("v_permlane16_swap_b32 %0, %1" : "+v"(w1), "+v"(w3));                     \
    union { int4 i4; s16x8 s8; } apu;                                             \
    apu.i4 = make_int4((int)w0, (int)w1, (int)w2, (int)w3);                       \
    s16x8 ap = apu.s8;                                                            \
    lac = __builtin_amdgcn_mfma_f32_16x16x32_bf16(ap, ones, lac, 0, 0, 0);        \
    o0  = __builtin_amdgcn_mfma_f32_16x16x32_bf16(ap, bv0, o0, 0, 0, 0);          \
    o1  = __builtin_amdgcn_mfma_f32_16x16x32_bf16(ap, bv1, o1, 0, 0, 0);          \
} while (0)

__global__ __launch_bounds__(256, 8) void k_attn(const short* __restrict__ qT,
        const short* __restrict__ kT, const short* __restrict__ vB,
        short* __restrict__ po0, short* __restrict__ po1,
        float* __restrict__ pl) {
    __shared__ __align__(16) short pool[8192];
    int xb  = blockIdx.x;
    int rm  = (xb & 7) * 128 + (xb >> 3);      // XCD-bijective swizzle
    int bh  = rm >> 6;
    int wid = threadIdx.x >> 6;
    int i0  = (rm & 63) * 64 + wid * 16;
    int s   = blockIdx.y;
    int jb  = s * JL;
    int lane = threadIdx.x & 63;
    int lr = lane & 15, lg = lane >> 4;
    const short* qTb = qT + (size_t)bh * N * 32;
    const short* kTb = kT + (size_t)bh * N * 32;
    const short* vBb = vB + (size_t)bh * 32 * N;

    s16x8 aq = *(const s16x8*)(qTb + (i0 + lr) * 32 + lg * 8);
    s16x8 ones;
    #pragma unroll
    for (int e = 0; e < 8; ++e) ones[e] = (short)0x3F80;

    f32x4 o0 = {0,0,0,0}, o1 = {0,0,0,0}, lac = {0,0,0,0};
    const f32x4 zero = {0,0,0,0};

    int krow  = 16 * wid + (lane >> 2);
    int kslot = lane & 3;
    const short* kg = kTb + (size_t)(jb + krow) * 32 + kslot * 8;
    int kw_ofs = krow * 32 + ((kslot ^ (krow & 3)) * 8);

    int vrow  = 8 * wid + (lane >> 3);
    int vslot = lane & 7;
    const short* vg = vBb + (size_t)vrow * N + jb + vslot * 8;
    int vw_ofs = vrow * 64 + ((vslot ^ (vrow & 7)) * 8);

    int kr_base = lr * 32 + ((lg ^ (lr & 3)) * 8);
    int vr0 = lr * 64, vr1 = (16 + lr) * 64;
    int sw0 = ((0 + lg) ^ (lr & 7)) * 8;
    int sw1 = ((4 + lg) ^ (lr & 7)) * 8;

    {
        s16x8 kreg = *(const s16x8*)kg;
        s16x8 vreg = *(const s16x8*)vg;
        *(s16x8*)&pool[kw_ofs] = kreg;
        *(s16x8*)&pool[4096 + vw_ofs] = vreg;
    }
    __syncthreads();

    for (int t = 0; t < 32; ++t) {
        int p = t & 1;
        s16x8 nk, nv;
        if (t < 31) {
            nk = *(const s16x8*)(kg + (t + 1) * 2048);
            nv = *(const s16x8*)(vg + (t + 1) * 64);
        }
        const short* lkp = &pool[p * 2048];
        const short* lvp = &pool[4096 + p * 2048];
        {
            s16x8 bk0 = *(const s16x8*)(lkp + kr_base);
            s16x8 bk1 = *(const s16x8*)(lkp + 512 + kr_base);
            s16x8 bv0 = *(const s16x8*)(lvp + vr0 + sw0);
            s16x8 bv1 = *(const s16x8*)(lvp + vr1 + sw0);
            TILE_BODY();
        }
        {
            s16x8 bk0 = *(const s16x8*)(lkp + 1024 + kr_base);
            s16x8 bk1 = *(const s16x8*)(lkp + 1536 + kr_base);
            s16x8 bv0 = *(const s16x8*)(lvp + vr0 + sw1);
            s16x8 bv1 = *(const s16x8*)(lvp + vr1 + sw1);
            TILE_BODY();
        }
        if (t < 31) {
            int q = (t + 1) & 1;
            *(s16x8*)&pool[q * 2048 + kw_ofs] = nk;
            *(s16x8*)&pool[4096 + q * 2048 + vw_ofs] = nv;
        }
        __syncthreads();
    }

    #pragma unroll
    for (int r = 0; r < 4; ++r) {
        pool[wid * 640 + (4 * lg + r) * 40 + lr]      = f2bf(o0[r]);
        pool[wid * 640 + (4 * lg + r) * 40 + 16 + lr] = f2bf(o1[r]);
    }
    if (lr == 0) {
        float* plp = pl + ((size_t)(s * 16 + bh)) * N + i0;
        #pragma unroll
        for (int r = 0; r < 4; ++r) plp[4 * lg + r] = lac[r];
    }
    short* pob = s ? po1 : po0;
    int il = lane >> 2, seg = lane & 3;
    s16x8 w = *(const s16x8*)&pool[wid * 640 + il * 40 + seg * 8];
    short* op = pob + ((size_t)bh * N + i0 + il) * 32 + seg * 8;
    *(s16x8*)op = w;
}

// ---------------- K6: out projection + residual; merge folded into staging --------
// n-tile 32 -> 1024 blocks, 16KB LDS (4 blocks/CU). grid (4,128,2), mb fastest.
__global__ __launch_bounds__(256) void k_out(const short* __restrict__ wob,
        const short* __restrict__ po0, const short* __restrict__ po1,
        const float* __restrict__ pl, const float* __restrict__ bo,
        const float* __restrict__ x, float* __restrict__ out) {
    __shared__ __align__(16) short bs[8 * 32 * 32];   // 16KB: 8 h-tiles swizzled
    int mb = blockIdx.x, nb = blockIdx.y, b = blockIdx.z;
    int n0 = nb * 32;
    int t = threadIdx.x;
    int wid = t >> 6, lane = t & 63;
    int lr = lane & 15, lg = lane >> 4;
    int mw = mb * 64 + wid * 16;

    const short* ap_ = wob + (mw + lr) * C + lg * 8;
    s16x8 af[8];
    #pragma unroll
    for (int h = 0; h < 8; ++h) af[h] = *(const s16x8*)(ap_ + h * 32);

    {
        int h = t >> 5, idx = t & 31;
        size_t rb = ((size_t)(b * 8 + h)) * N + n0;
        const short* g0 = po0 + rb * 32;
        const short* g1 = po1 + rb * 32;
        const float* pl0 = pl + rb;
        const float* pl1 = pl + ((size_t)(16 + b * 8 + h)) * N + n0;
        #pragma unroll
        for (int i = 0; i < 4; ++i) {
            int chunk = idx + 32 * i;           // 0..127
            int r = chunk >> 2, sl = chunk & 3; // r: n-local 0..31
            s16x8 v0 = *(const s16x8*)(g0 + r * 32 + sl * 8);
            s16x8 v1 = *(const s16x8*)(g1 + r * 32 + sl * 8);
            float inv = 1.f / (pl0[r] + pl1[r]);
            s16x8 w;
            #pragma unroll
            for (int e = 0; e < 8; ++e)
                w[e] = f2bf((bf2f(v0[e]) + bf2f(v1[e])) * inv);
            *(s16x8*)&bs[h * 1024 + r * 32 + ((sl ^ (r & 3)) * 8)] = w;
        }
    }
    __syncthreads();

    f32x4 acc[2] = {{0,0,0,0},{0,0,0,0}};
    #pragma unroll
    for (int h = 0; h < 8; ++h) {
        #pragma unroll
        for (int f = 0; f < 2; ++f) {
            int row = f * 16 + lr;
            s16x8 xf = *(const s16x8*)&bs[h * 1024 + row * 32 + ((lg ^ (lr & 3)) * 8)];
            acc[f] = __builtin_amdgcn_mfma_f32_16x16x32_bf16(af[h], xf, acc[f], 0, 0, 0);
        }
    }

    float bvals[4];
    #pragma unroll
    for (int r = 0; r < 4; ++r) bvals[r] = bo[mw + 4 * lg + r];
    #pragma unroll
    for (int f = 0; f < 2; ++f) {
        int n = n0 + f * 16 + lr;
        #pragma unroll
        for (int r = 0; r < 4; ++r) {
            size_t idx = (size_t)(b * C + mw + 4 * lg + r) * N + n;
            out[idx] = acc[f][r] + bvals[r] + x[idx];
        }
    }
}

extern "C" void kernel_launch(void* const* d_in, const int* in_sizes, int n_in,
                              void* d_out, int out_size, void* d_ws, size_t ws_size,
                              hipStream_t stream) {
    const float* x  = (const float*)d_in[0];
    const float* gs = (const float*)d_in[1];
    const float* gb = (const float*)d_in[2];
    const float* wq = (const float*)d_in[3];
    const float* bq = (const float*)d_in[4];
    const float* wk = (const float*)d_in[5];
    const float* bk = (const float*)d_in[6];
    const float* wv = (const float*)d_in[7];
    const float* bv = (const float*)d_in[8];
    const float* wo = (const float*)d_in[9];
    const float* bo = (const float*)d_in[10];
    float* out = (float*)d_out;
    char* ws = (char*)d_ws;

    // Total ws usage: 0x14B0000 = 21.69 MB (< 22.02 MB proven safe).
    float2* partials = (float2*)(ws);           // 2 KB
    short*  wqkvb = (short*)(ws + 0x1000);      // 384 KB, dead after k_qkv
    float*  pl    = (float*)(ws + 0x1000);      // 512 KB, overlays dead wqkvb
    short*  wob   = (short*)(ws + 0x81000);     // 128 KB
    short*  xnT   = (short*)(ws + 0xB0000);     // 4 MB [b][n][c], dead after k_qkv
    short*  po1   = (short*)(ws + 0xB0000);     // 4 MB, overlays dead xnT
    short*  qT    = (short*)(ws + 0x4B0000);    // 4 MB [bh][n][32]
    short*  kT    = (short*)(ws + 0x8B0000);    // 4 MB [bh][n][32]
    short*  vB    = (short*)(ws + 0xCB0000);    // 4 MB [bh][32][n]
    short*  po0   = (short*)(ws + 0x10B0000);   // 4 MB [bh][n][32]

    k_stats<<<256, 256, 0, stream>>>(x, partials);
    k_wcvt <<<1024, 256, 0, stream>>>(wq, wk, wv, wo, wqkvb, wob);
    k_t    <<<512, 256, 0, stream>>>(x, gs, gb, partials, xnT);
    k_qkv  <<<dim3(12, 64, 2), 256, 0, stream>>>(wqkvb, xnT, bq, bk, bv, qT, kT, vB);
    k_attn <<<dim3(1024, 2), 256, 0, stream>>>(qT, kT, vB, po0, po1, pl);
    k_out  <<<dim3(4, 128, 2), 256, 0, stream>>>(wob, po0, po1, pl, bo, x, out);
}